// Round 1
// baseline (52.706 us; speedup 1.0000x reference)
//
#include <hip/hip_runtime.h>
#include <math.h>

namespace {

constexpr int L = 64;       // chunk size
constexpr int DH = 64;      // head dim
constexpr int STRIDE = 68;  // floats per padded row (272 B, 16B-aligned)

__device__ __forceinline__ int swz4(int row, int col4) {
  // XOR a row-derived value into the float4-column index so that
  // "same col4, varying row" reads spread across all 8 bank-groups.
  return col4 ^ ((row >> 3) & 7);
}

__global__ __launch_bounds__(256) void mlstm_intra(
    const float* __restrict__ q, const float* __restrict__ k,
    const float* __restrict__ v, const float* __restrict__ ig,
    const float* __restrict__ fg, float* __restrict__ out) {

  __shared__ __align__(16) float q_s[L * STRIDE];  // later reused to hold C
  __shared__ __align__(16) float k_s[L * STRIDE];
  __shared__ __align__(16) float v_s[L * STRIDE];
  __shared__ float a_sh[L];
  __shared__ float b_sh[L];
  __shared__ float em_sh[L];

  const int tid = threadIdx.x;
  const size_t base = (size_t)blockIdx.x * (L * DH);

  // ---- stage q,k,v into LDS (swizzled float4 writes, coalesced global) ----
  {
    const float4* __restrict__ q4 = (const float4*)(q + base);
    const float4* __restrict__ k4 = (const float4*)(k + base);
    const float4* __restrict__ v4 = (const float4*)(v + base);
#pragma unroll
    for (int it = 0; it < 4; ++it) {
      const int idx = tid + it * 256;   // float4 index, 0..1023
      const int row = idx >> 4;
      const int c4 = idx & 15;
      const int off = row * STRIDE + 4 * swz4(row, c4);
      *(float4*)&q_s[off] = q4[idx];
      *(float4*)&k_s[off] = k4[idx];
      *(float4*)&v_s[off] = v4[idx];
    }
  }

  // ---- gates: wave 0 computes a[j], b[i] (prefix max), exp(-m[i]) ----
  if (tid < 64) {
    const float x = fg[(size_t)blockIdx.x * L + tid];
    // log_sigmoid(x) = min(x,0) - log1p(exp(-|x|))
    const float lf = fminf(x, 0.f) - log1pf(expf(-fabsf(x)));
    float cum = lf;  // inclusive prefix sum of log forget gates
#pragma unroll
    for (int o = 1; o < 64; o <<= 1) {
      const float t = __shfl_up(cum, o, 64);
      if (tid >= o) cum += t;
    }
    const float a = ig[(size_t)blockIdx.x * L + tid] - cum;
    float b = a;  // inclusive prefix max of a
#pragma unroll
    for (int o = 1; o < 64; o <<= 1) {
      const float t = __shfl_up(b, o, 64);
      if (tid >= o) b = fmaxf(b, t);
    }
    a_sh[tid] = a;
    b_sh[tid] = b;
    em_sh[tid] = expf(-(b + cum));  // exp(-m[i])
  }
  __syncthreads();

  const int r = tid >> 4;  // row group: rows 4r..4r+3
  const int c = tid & 15;  // col group: cols 4c..4c+3

  // ---- matmul 1: S = Q K^T (per-thread 4x4 tile) ----
  float acc[4][4] = {};
#pragma unroll 4
  for (int d4 = 0; d4 < 16; ++d4) {
    float qv[4][4], kv[4][4];
#pragma unroll
    for (int ii = 0; ii < 4; ++ii) {
      const int row = 4 * r + ii;
      *(float4*)qv[ii] = *(const float4*)&q_s[row * STRIDE + 4 * swz4(row, d4)];
    }
#pragma unroll
    for (int jj = 0; jj < 4; ++jj) {
      const int row = 4 * c + jj;
      *(float4*)kv[jj] = *(const float4*)&k_s[row * STRIDE + 4 * swz4(row, d4)];
    }
#pragma unroll
    for (int ii = 0; ii < 4; ++ii)
#pragma unroll
      for (int jj = 0; jj < 4; ++jj)
#pragma unroll
        for (int dd = 0; dd < 4; ++dd)
          acc[ii][jj] = fmaf(qv[ii][dd], kv[jj][dd], acc[ii][jj]);
  }

  // ---- apply decay gating, row-sum, stabilized normalizer ----
  float inv[4];
#pragma unroll
  for (int ii = 0; ii < 4; ++ii) {
    const int i = 4 * r + ii;
    const float bi = b_sh[i];
    float rs = 0.f;
#pragma unroll
    for (int jj = 0; jj < 4; ++jj) {
      const int j = 4 * c + jj;
      const float cv =
          (j <= i) ? acc[ii][jj] * 0.125f * __expf(a_sh[j] - bi) : 0.f;
      acc[ii][jj] = cv;
      rs += cv;
    }
    // reduce row sum across the 16 lanes that share this row group
#pragma unroll
    for (int o = 1; o < 16; o <<= 1) rs += __shfl_xor(rs, o, 64);
    const float n = fmaxf(fabsf(rs), em_sh[i]);
    inv[ii] = 1.f / (n + 1e-6f);
  }

  // ---- write C back into q_s (reuse) ----
  __syncthreads();  // all matmul-1 q reads done
#pragma unroll
  for (int ii = 0; ii < 4; ++ii) {
    const int row = 4 * r + ii;
    *(float4*)&q_s[row * STRIDE + 4 * swz4(row, c)] =
        make_float4(acc[ii][0], acc[ii][1], acc[ii][2], acc[ii][3]);
  }
  __syncthreads();

  // ---- matmul 2: H = C V, wave-uniform causal bound ----
  float h[4][4] = {};
  const int j4max = 4 * (tid >> 6) + 3;  // wave w covers rows < 16(w+1)
#pragma unroll 4
  for (int j4 = 0; j4 <= j4max; ++j4) {
    float cvf[4][4], vvf[4][4];
#pragma unroll
    for (int ii = 0; ii < 4; ++ii) {
      const int row = 4 * r + ii;
      *(float4*)cvf[ii] = *(const float4*)&q_s[row * STRIDE + 4 * swz4(row, j4)];
    }
#pragma unroll
    for (int jj = 0; jj < 4; ++jj) {
      const int row = 4 * j4 + jj;
      *(float4*)vvf[jj] = *(const float4*)&v_s[row * STRIDE + 4 * swz4(row, c)];
    }
#pragma unroll
    for (int ii = 0; ii < 4; ++ii)
#pragma unroll
      for (int dd = 0; dd < 4; ++dd) {
        float s = h[ii][dd];
#pragma unroll
        for (int jj = 0; jj < 4; ++jj) s = fmaf(cvf[ii][jj], vvf[jj][dd], s);
        h[ii][dd] = s;
      }
  }

  // ---- normalize rows and store (coalesced float4) ----
  float4* __restrict__ out4 = (float4*)(out + base);
#pragma unroll
  for (int ii = 0; ii < 4; ++ii) {
    out4[(4 * r + ii) * 16 + c] =
        make_float4(h[ii][0] * inv[ii], h[ii][1] * inv[ii],
                    h[ii][2] * inv[ii], h[ii][3] * inv[ii]);
  }
}

}  // namespace

extern "C" void kernel_launch(void* const* d_in, const int* in_sizes, int n_in,
                              void* d_out, int out_size, void* d_ws,
                              size_t ws_size, hipStream_t stream) {
  const float* q = (const float*)d_in[0];
  const float* k = (const float*)d_in[1];
  const float* v = (const float*)d_in[2];
  const float* ig = (const float*)d_in[3];
  const float* fg = (const float*)d_in[4];
  float* out = (float*)d_out;

  const int total = in_sizes[0];          // B*NH*S*DH
  const int nchunks = total / (L * DH);   // B*NH*NC = 2048
  mlstm_intra<<<dim3(nchunks), dim3(256), 0, stream>>>(q, k, v, ig, fg, out);
}

// Round 2
// 27.630 us; speedup vs baseline: 1.9076x; 1.9076x over previous
//
#include <hip/hip_runtime.h>
#include <hip/hip_bf16.h>
#include <math.h>

namespace {

typedef __bf16 bf16x8 __attribute__((ext_vector_type(8)));
typedef float f32x4 __attribute__((ext_vector_type(4)));

constexpr int L = 64;
constexpr int DH = 64;

// Byte offset of bf16 element (row,col) in a 64x64 row-major bf16 LDS tile
// (row stride 128 B) with a 16B-slot XOR swizzle: kills the 16-way bank
// conflict of "16 lanes read 16 rows at the same column slot" (G4/T2).
// Used for BOTH writes and reads (rule #21: both-sides-or-neither).
__device__ __forceinline__ int swz(int row, int col) {
  return row * 128 + ((((col >> 3) ^ (row & 7)) << 4)) + (col & 7) * 2;
}

__device__ __forceinline__ unsigned short bfbits(float f) {
  __bf16 h = (__bf16)f;
  return __builtin_bit_cast(unsigned short, h);
}
__device__ __forceinline__ __bf16 tobf(float f) { return (__bf16)f; }

__global__ __launch_bounds__(64) void mlstm_mfma(
    const float* __restrict__ q, const float* __restrict__ k,
    const float* __restrict__ v, const float* __restrict__ ig,
    const float* __restrict__ fg, float* __restrict__ out) {

  // One wave (64 threads) owns one 64x64 chunk. No __syncthreads anywhere.
  __shared__ __align__(16) char vt_raw[64 * 128];  // V^T bf16, swizzled
  __shared__ __align__(16) char cs_raw[64 * 128];  // C   bf16, swizzled
  __shared__ float ea_sh[64], eb_sh[64], em_sh[64], inv_sh[64];

  const int lane = threadIdx.x;
  const int m = lane & 15;   // fragment row/col index
  const int g = lane >> 4;   // fragment k-group
  const size_t cbase = (size_t)blockIdx.x * (L * DH);

  // ---------------- gates: two 64-lane scans, 5 exps per lane ------------
  {
    const size_t gb = (size_t)blockIdx.x * L;
    const float x = fg[gb + lane];
    const float lf = fminf(x, 0.f) - log1pf(__expf(-fabsf(x)));
    float cum = lf;  // inclusive prefix sum of log f
#pragma unroll
    for (int o = 1; o < 64; o <<= 1) {
      const float t = __shfl_up(cum, o, 64);
      if (lane >= o) cum += t;
    }
    const float a = ig[gb + lane] - cum;  // a[j] = ig[j] - cum[j]
    float b = a;                          // b[i] = prefix max of a
#pragma unroll
    for (int o = 1; o < 64; o <<= 1) {
      const float t = __shfl_up(b, o, 64);
      if (lane >= o) b = fmaxf(b, t);
    }
    const float bmax = __shfl(b, 63, 64);
    // D[i][j] = exp(a[j]-b[i]) = ea'[j]*eb[i]; fold the 1/sqrt(DH) scale.
    ea_sh[lane] = 0.125f * __expf(a - bmax);
    eb_sh[lane] = __expf(bmax - b);
    em_sh[lane] = __expf(-(b + cum));  // exp(-m[i])
  }

  // ---------------- stage V^T into LDS (bf16, swizzled) ------------------
  {
    const float4* v4 = (const float4*)(v + cbase);
    float4 buf[16];
#pragma unroll
    for (int it = 0; it < 16; ++it) buf[it] = v4[it * 64 + lane];
    unsigned short* vt = (unsigned short*)vt_raw;
#pragma unroll
    for (int it = 0; it < 16; ++it) {
      const int idx = it * 64 + lane;   // float4 index in the chunk
      const int j = idx >> 4;           // source row (time index)
      const int d0 = (idx & 15) * 4;    // source col (feature)
      vt[swz(d0 + 0, j) >> 1] = bfbits(buf[it].x);
      vt[swz(d0 + 1, j) >> 1] = bfbits(buf[it].y);
      vt[swz(d0 + 2, j) >> 1] = bfbits(buf[it].z);
      vt[swz(d0 + 3, j) >> 1] = bfbits(buf[it].w);
    }
  }

  // ------------- Q,K fragments: global -> registers, cvt bf16 ------------
  // mm1 computes S^T = K * Q^T. A-frag: row j = rb*16+m, k = d contiguous.
  // B-frag: col i = cb*16+m, k = d contiguous. Both natural row-major.
  bf16x8 kf[4][2], qf[4][2];
#pragma unroll
  for (int rb = 0; rb < 4; ++rb)
#pragma unroll
    for (int kb = 0; kb < 2; ++kb) {
      const int off = (rb * 16 + m) * 64 + kb * 32 + g * 8;
      const float4 k0 = *(const float4*)(k + cbase + off);
      const float4 k1 = *(const float4*)(k + cbase + off + 4);
      const float4 q0 = *(const float4*)(q + cbase + off);
      const float4 q1 = *(const float4*)(q + cbase + off + 4);
      kf[rb][kb] = bf16x8{tobf(k0.x), tobf(k0.y), tobf(k0.z), tobf(k0.w),
                          tobf(k1.x), tobf(k1.y), tobf(k1.z), tobf(k1.w)};
      qf[rb][kb] = bf16x8{tobf(q0.x), tobf(q0.y), tobf(q0.z), tobf(q0.w),
                          tobf(q1.x), tobf(q1.y), tobf(q1.z), tobf(q1.w)};
    }

  // ---------------- mm1: S^T tiles (only rb <= cb are causal) ------------
  f32x4 st[4][4];
#pragma unroll
  for (int cb = 0; cb < 4; ++cb)
#pragma unroll
    for (int rb = 0; rb < 4; ++rb) {
      if (rb > cb) continue;
      f32x4 acc = {0.f, 0.f, 0.f, 0.f};
      acc = __builtin_amdgcn_mfma_f32_16x16x32_bf16(kf[rb][0], qf[cb][0], acc, 0, 0, 0);
      acc = __builtin_amdgcn_mfma_f32_16x16x32_bf16(kf[rb][1], qf[cb][1], acc, 0, 0, 0);
      st[rb][cb] = acc;
    }

  // -------- gating, row-sum, normalizer; write C (bf16) to LDS -----------
  float ea_j[4][4];
#pragma unroll
  for (int rb = 0; rb < 4; ++rb)
#pragma unroll
    for (int e = 0; e < 4; ++e) ea_j[rb][e] = ea_sh[rb * 16 + g * 4 + e];

#pragma unroll
  for (int cb = 0; cb < 4; ++cb) {
    const int i = cb * 16 + m;
    const float ebv = eb_sh[i];
    float rs = 0.f;
#pragma unroll
    for (int rb = 0; rb < 4; ++rb) {
      unsigned long long wp = 0ull;  // 4 packed bf16 (j = rb*16+g*4 .. +3)
      if (rb <= cb) {
#pragma unroll
        for (int e = 0; e < 4; ++e) {
          const int j = rb * 16 + g * 4 + e;
          const float val =
              (j <= i) ? st[rb][cb][e] * ea_j[rb][e] * ebv : 0.f;
          rs += val;
          wp |= (unsigned long long)bfbits(val) << (16 * e);
        }
      }
      // zero-fill masked tiles too: mm2 fragment reads cover the full row
      *(unsigned long long*)(cs_raw + swz(i, rb * 16 + g * 4)) = wp;
    }
    rs += __shfl_xor(rs, 16, 64);
    rs += __shfl_xor(rs, 32, 64);
    const float n = fmaxf(fabsf(rs), em_sh[i]);
    inv_sh[i] = 1.f / (n + 1e-6f);  // same value from all 4 k-groups
  }

  // ---------------- mm2: H^T = V^T * C^T ---------------------------------
  // A-frag: V^T row d = db*16+m, k = j contiguous (from swizzled vt).
  // B-frag: C^T col i = ib*16+m, k = j contiguous (= row i of C in cs).
  bf16x8 vfr[4][2];
#pragma unroll
  for (int db = 0; db < 4; ++db)
#pragma unroll
    for (int jb = 0; jb < 2; ++jb)
      vfr[db][jb] =
          *(const bf16x8*)(vt_raw + swz(db * 16 + m, jb * 32 + g * 8));

  bf16x8 cfr[4][2];
#pragma unroll
  for (int ib = 0; ib < 4; ++ib) {
    cfr[ib][0] = *(const bf16x8*)(cs_raw + swz(ib * 16 + m, g * 8));
    if (ib >= 2)
      cfr[ib][1] = *(const bf16x8*)(cs_raw + swz(ib * 16 + m, 32 + g * 8));
  }

  f32x4 hh[4][4];  // [ib][db]
#pragma unroll
  for (int ib = 0; ib < 4; ++ib)
#pragma unroll
    for (int db = 0; db < 4; ++db) {
      f32x4 acc = {0.f, 0.f, 0.f, 0.f};
      acc = __builtin_amdgcn_mfma_f32_16x16x32_bf16(vfr[db][0], cfr[ib][0], acc, 0, 0, 0);
      if (ib >= 2)
        acc = __builtin_amdgcn_mfma_f32_16x16x32_bf16(vfr[db][1], cfr[ib][1], acc, 0, 0, 0);
      hh[ib][db] = acc;
    }

  // ---------------- normalize + store (float4, coalesced) ----------------
#pragma unroll
  for (int ib = 0; ib < 4; ++ib) {
    const int i = ib * 16 + m;
    const float iv = inv_sh[i];
    float* op = out + cbase + i * 64 + g * 4;
#pragma unroll
    for (int db = 0; db < 4; ++db) {
      const f32x4 hv = hh[ib][db];
      *(float4*)(op + db * 16) =
          make_float4(hv[0] * iv, hv[1] * iv, hv[2] * iv, hv[3] * iv);
    }
  }
}

}  // namespace

extern "C" void kernel_launch(void* const* d_in, const int* in_sizes, int n_in,
                              void* d_out, int out_size, void* d_ws,
                              size_t ws_size, hipStream_t stream) {
  const float* q = (const float*)d_in[0];
  const float* k = (const float*)d_in[1];
  const float* v = (const float*)d_in[2];
  const float* ig = (const float*)d_in[3];
  const float* fg = (const float*)d_in[4];
  float* out = (float*)d_out;

  const int total = in_sizes[0];         // B*NH*S*DH
  const int nchunks = total / (L * DH);  // 2048
  mlstm_mfma<<<dim3(nchunks), dim3(64), 0, stream>>>(q, k, v, ig, fg, out);
}